// Round 6
// baseline (503.928 us; speedup 1.0000x reference)
//
#include <hip/hip_runtime.h>
#include <hip/hip_bf16.h>

typedef unsigned short u16;
typedef unsigned int   u32;
typedef __bf16 bf16x8 __attribute__((ext_vector_type(8)));
typedef float  f32x4  __attribute__((ext_vector_type(4)));

#define NB 4
#define T_ 2048
#define D_ 1024
#define H_ 16
#define DH 64
#define M_ (NB * T_)   // 8192 rows
#define PSTR 72        // padded LDS row stride (elements) for 64-wide tiles

__device__ __forceinline__ float bf2f(u16 u) {
    union { u32 i; float f; } v; v.i = ((u32)u) << 16; return v.f;
}
__device__ __forceinline__ u16 f2bf(float f) {
    union { float fl; u32 i; } v; v.fl = f;
    u32 r = v.i + 0x7fff + ((v.i >> 16) & 1);
    return (u16)(r >> 16);
}

// async global->LDS, 16B per lane; LDS dest = wave-uniform base + lane*16
__device__ __forceinline__ void gld16(const u16* g, u16* l) {
    __builtin_amdgcn_global_load_lds(
        (const __attribute__((address_space(1))) void*)g,
        (__attribute__((address_space(3))) void*)l,
        16, 0, 0);
}

// ---------------------------------------------------------- dtype detector
__device__ __forceinline__ int detect_f32(const u16* p) {
    int weird = 0;
    const int lane = threadIdx.x & 63;
    #pragma unroll
    for (int i = 0; i < 4; ++i) {
        const u16 u = p[lane * 4 + i];
        const int e = (u >> 7) & 0xFF;
        weird += (e == 0xFF || (e >= 0x01 && e <= 0x3F) || (e >= 0xC0 && e <= 0xFE));
    }
    #pragma unroll
    for (int off = 32; off; off >>= 1) weird += __shfl_xor(weird, off);
    return weird >= 16;
}

// int32/int64-tolerant sequence-length read
__device__ __forceinline__ int read_len(const void* raw, int b) {
    const int* a32 = (const int*)raw;
    bool ok32 = true;
    #pragma unroll
    for (int i = 0; i < NB; ++i) {
        const int v = a32[i];
        if (v < 1 || v > T_) ok32 = false;
    }
    int v = ok32 ? a32[b] : (int)((const long long*)raw)[b];
    return min(max(v, 1), T_);
}

// ---------------------------------------------------------------- LayerNorm
__global__ __launch_bounds__(256) void ln_kernel(const void* __restrict__ xraw,
                                                 const void* __restrict__ graw,
                                                 const void* __restrict__ braw,
                                                 u16* __restrict__ h) {
    const int row = blockIdx.x;
    const int tid = threadIdx.x;
    const int isf = detect_f32((const u16*)xraw);

    float xv[4];
    if (isf) {
        const float* xr = (const float*)xraw + (size_t)row * D_;
        *(float4*)xv = *(const float4*)&xr[tid * 4];
    } else {
        const u16* xr = (const u16*)xraw + (size_t)row * D_;
        u16 loc[4] __attribute__((aligned(8)));
        *(uint2*)loc = *(const uint2*)&xr[tid * 4];
        #pragma unroll
        for (int i = 0; i < 4; ++i) xv[i] = bf2f(loc[i]);
    }

    float s = xv[0] + xv[1] + xv[2] + xv[3];
    float q = xv[0]*xv[0] + xv[1]*xv[1] + xv[2]*xv[2] + xv[3]*xv[3];

    #pragma unroll
    for (int off = 32; off; off >>= 1) {
        s += __shfl_xor(s, off);
        q += __shfl_xor(q, off);
    }
    __shared__ float red[8];
    const int wave = tid >> 6, lane = tid & 63;
    if (lane == 0) { red[wave] = s; red[4 + wave] = q; }
    __syncthreads();
    s = red[0] + red[1] + red[2] + red[3];
    q = red[4] + red[5] + red[6] + red[7];

    const float mean = s * (1.0f / D_);
    const float var  = q * (1.0f / D_) - mean * mean;
    const float rs   = rsqrtf(var + 1e-5f);

    u16 o[4] __attribute__((aligned(8)));
    #pragma unroll
    for (int i = 0; i < 4; ++i) {
        const int c = tid * 4 + i;
        const float gv = isf ? ((const float*)graw)[c] : bf2f(((const u16*)graw)[c]);
        const float bv = isf ? ((const float*)braw)[c] : bf2f(((const u16*)braw)[c]);
        o[i] = f2bf((xv[i] - mean) * rs * gv + bv);
    }
    *(uint2*)&h[(size_t)row * D_ + tid * 4] = *(uint2*)o;
}

// ------------------------------------------------- weight transpose+convert
// Wt[n][k] (bf16) from W[k][n] (f32 or bf16). 64x64 tiles via LDS.
__global__ __launch_bounds__(256) void wconv_kernel(const void* __restrict__ Wraw,
                                                    u16* __restrict__ Wt) {
    __shared__ u16 tile[64][PSTR];
    const int isf = detect_f32((const u16*)Wraw);
    const int n0 = blockIdx.x * 64;
    const int k0 = blockIdx.y * 64;
    const int tid = threadIdx.x;
    const int tr  = tid >> 2;          // 0..63
    const int tc  = (tid & 3) * 16;    // 0,16,32,48

    if (isf) {
        const float* W = (const float*)Wraw;
        #pragma unroll
        for (int i = 0; i < 16; ++i)
            tile[tc + i][tr] = f2bf(W[(size_t)(k0 + tr) * D_ + n0 + tc + i]);
    } else {
        const u16* W = (const u16*)Wraw;
        #pragma unroll
        for (int i = 0; i < 16; ++i)
            tile[tc + i][tr] = W[(size_t)(k0 + tr) * D_ + n0 + tc + i];
    }
    __syncthreads();
    *(uint4*)&Wt[(size_t)(n0 + tr) * D_ + k0 + tc]     = *(uint4*)&tile[tr][tc];
    *(uint4*)&Wt[(size_t)(n0 + tr) * D_ + k0 + tc + 8] = *(uint4*)&tile[tr][tc + 8];
}

// --------------------------------------------------------- GEMM 128x128
// m97-style: BK=32, global_load_lds width-16 staging (contiguous LDS, no
// padding — wave-uniform base + lane*16), 4 waves 2x2, each 64x64 via 4x4
// mfma 16x16x32. Bt = bf16 [n][k]. Braw only used for output-dtype detect.
// mode 0: row-major store (f32 if orig weights f32) ; 1: V^T scatter ;
// mode 2: (N,H,T,DH) scatter + RoPE
__global__ __launch_bounds__(256) void gemm128_kernel(const u16* __restrict__ A,
                                                      const u16* __restrict__ Bt,
                                                      const void* __restrict__ Braw,
                                                      const void* __restrict__ biasraw,
                                                      void* __restrict__ out,
                                                      const int mode) {
    __shared__ __align__(16) u16 As[128 * 32];
    __shared__ __align__(16) u16 Bs[128 * 32];

    const int tid   = threadIdx.x;
    const int ntile = blockIdx.x * 128;
    const int mtile = blockIdx.y * 128;
    const int wv    = tid >> 6;
    const int ln    = tid & 63;
    const int quad  = ln >> 4;
    const int lr    = ln & 15;
    const int wy    = wv >> 1;      // 0,1 : M half
    const int wx    = wv & 1;       // 0,1 : N half

    const int isf = detect_f32((const u16*)Braw);
    const int isfb = detect_f32((const u16*)biasraw);

    f32x4 acc[4][4];
    #pragma unroll
    for (int mt = 0; mt < 4; ++mt)
        #pragma unroll
        for (int nt = 0; nt < 4; ++nt)
            acc[mt][nt] = (f32x4){0.f, 0.f, 0.f, 0.f};

    // staging: wave wv covers rows wv*32 .. wv*32+31 (two 1KB issues)
    const int srow = wv * 32 + (ln >> 2);       // rows for chunk 0
    const int skb  = (ln & 3) * 8;              // k-chunk (elems)
    const u16* gA0 = A  + (size_t)(mtile + srow) * D_ + skb;
    const u16* gA1 = gA0 + (size_t)16 * D_;
    const u16* gB0 = Bt + (size_t)(ntile + srow) * D_ + skb;
    const u16* gB1 = gB0 + (size_t)16 * D_;
    u16* lA0 = As + wv * 1024;          // bytes: wv*2048
    u16* lA1 = lA0 + 512;               // +1024 B
    u16* lB0 = Bs + wv * 1024;
    u16* lB1 = lB0 + 512;

    for (int k0 = 0; k0 < D_; k0 += 32) {
        gld16(gA0 + k0, lA0);
        gld16(gA1 + k0, lA1);
        gld16(gB0 + k0, lB0);
        gld16(gB1 + k0, lB1);
        __syncthreads();   // drains vmcnt (incl. global_load_lds) + barrier

        bf16x8 af[4], bfr[4];
        #pragma unroll
        for (int mt = 0; mt < 4; ++mt)
            af[mt] = *(const bf16x8*)&As[(wy * 64 + mt * 16 + lr) * 32 + quad * 8];
        #pragma unroll
        for (int nt = 0; nt < 4; ++nt)
            bfr[nt] = *(const bf16x8*)&Bs[(wx * 64 + nt * 16 + lr) * 32 + quad * 8];
        #pragma unroll
        for (int mt = 0; mt < 4; ++mt)
            #pragma unroll
            for (int nt = 0; nt < 4; ++nt)
                acc[mt][nt] = __builtin_amdgcn_mfma_f32_16x16x32_bf16(af[mt], bfr[nt], acc[mt][nt], 0, 0, 0);
        __syncthreads();   // LDS reuse guard for next staging
    }

    // epilogue: per 16x16 tile, C row = quad*4+r, col = lr
    #pragma unroll
    for (int mt = 0; mt < 4; ++mt) {
        #pragma unroll
        for (int nt = 0; nt < 4; ++nt) {
            const int ncol = ntile + wx * 64 + nt * 16 + lr;
            const float bv = isfb ? ((const float*)biasraw)[ncol]
                                  : bf2f(((const u16*)biasraw)[ncol]);
            #pragma unroll
            for (int r = 0; r < 4; ++r) {
                const int mrow = mtile + wy * 64 + mt * 16 + quad * 4 + r;
                float v = acc[mt][nt][r] + bv;
                if (mode == 2) {
                    const float other = __shfl_xor(v, 1);
                    const int d = ncol & (DH - 1);
                    const int t = mrow & (T_ - 1);
                    const int i = d >> 1;
                    const float inv = exp2f(-(float)i * 0.41524101186092f);
                    const float ang = (float)t * inv;
                    const float cv = cosf(ang), sv = sinf(ang);
                    v = (d & 1) ? (other * sv + v * cv) : (v * cv - other * sv);
                }
                const int d  = ncol & (DH - 1);
                const int hh = ncol >> 6;
                const int t  = mrow & (T_ - 1);
                const int bb = mrow >> 11;
                if (mode == 0) {
                    if (isf) ((float*)out)[(size_t)mrow * D_ + ncol] = v;
                    else     ((u16*)out)[(size_t)mrow * D_ + ncol] = f2bf(v);
                } else if (mode == 1) {
                    ((u16*)out)[(((size_t)(bb * H_ + hh) * DH) + d) * T_ + t] = f2bf(v);
                } else {
                    ((u16*)out)[(((size_t)(bb * H_ + hh) * T_) + t) * DH + d] = f2bf(v);
                }
            }
        }
    }
}

// ---------------------------------------------------------------- GEMM (fallback, 128x64)
__global__ __launch_bounds__(256) void gemm_kernel(const u16* __restrict__ A,
                                                   const void* __restrict__ Braw,
                                                   const void* __restrict__ biasraw,
                                                   void* __restrict__ out,
                                                   const int mode) {
    __shared__ __align__(16) u16 As[128 * 32];
    __shared__ __align__(16) u16 Bs[64 * 32];

    const int tid   = threadIdx.x;
    const int ntile = blockIdx.x * 64;
    const int mtile = blockIdx.y * 128;
    const int wave  = tid >> 6;
    const int lane  = tid & 63;
    const int quad  = lane >> 4;
    const int lr    = lane & 15;

    const int isf = detect_f32((const u16*)Braw);
    const float* Bf = (const float*)Braw;
    const u16*   Bu = (const u16*)Braw;

    f32x4 acc[2][4];
    #pragma unroll
    for (int s = 0; s < 2; ++s)
        #pragma unroll
        for (int n = 0; n < 4; ++n)
            acc[s][n] = (f32x4){0.f, 0.f, 0.f, 0.f};

    const int ar  = tid >> 1;
    const int akb = (tid & 1) * 16;
    const int bn  = tid & 63;
    const int bkb = (tid >> 6) * 8;
    const u16* Arow = A + (size_t)(mtile + ar) * D_ + akb;
    const size_t bcol0 = (size_t)bkb * D_ + ntile + bn;

    for (int k0 = 0; k0 < D_; k0 += 32) {
        *(uint4*)&As[ar * 32 + akb]     = *(const uint4*)(Arow + k0);
        *(uint4*)&As[ar * 32 + akb + 8] = *(const uint4*)(Arow + k0 + 8);
        u16 tmp[8] __attribute__((aligned(16)));
        if (isf) {
            #pragma unroll
            for (int j = 0; j < 8; ++j) tmp[j] = f2bf(Bf[bcol0 + (size_t)(k0 + j) * D_]);
        } else {
            #pragma unroll
            for (int j = 0; j < 8; ++j) tmp[j] = Bu[bcol0 + (size_t)(k0 + j) * D_];
        }
        *(uint4*)&Bs[bn * 32 + bkb] = *(uint4*)tmp;
        __syncthreads();

        const int mbase = wave * 32;
        bf16x8 af0 = *(const bf16x8*)&As[(mbase +      lr) * 32 + quad * 8];
        bf16x8 af1 = *(const bf16x8*)&As[(mbase + 16 + lr) * 32 + quad * 8];
        #pragma unroll
        for (int nt = 0; nt < 4; ++nt) {
            bf16x8 bf = *(const bf16x8*)&Bs[(nt * 16 + lr) * 32 + quad * 8];
            acc[0][nt] = __builtin_amdgcn_mfma_f32_16x16x32_bf16(af0, bf, acc[0][nt], 0, 0, 0);
            acc[1][nt] = __builtin_amdgcn_mfma_f32_16x16x32_bf16(af1, bf, acc[1][nt], 0, 0, 0);
        }
        __syncthreads();
    }

    #pragma unroll
    for (int s2 = 0; s2 < 2; ++s2) {
        #pragma unroll
        for (int nt = 0; nt < 4; ++nt) {
            const int ncol = ntile + nt * 16 + lr;
            const float bv = isf ? ((const float*)biasraw)[ncol]
                                 : bf2f(((const u16*)biasraw)[ncol]);
            #pragma unroll
            for (int r = 0; r < 4; ++r) {
                const int mrow = mtile + wave * 32 + s2 * 16 + quad * 4 + r;
                float v = acc[s2][nt][r] + bv;
                if (mode == 2) {
                    const float other = __shfl_xor(v, 1);
                    const int d = ncol & (DH - 1);
                    const int t = mrow & (T_ - 1);
                    const int i = d >> 1;
                    const float inv = exp2f(-(float)i * 0.41524101186092f);
                    const float ang = (float)t * inv;
                    const float cv = cosf(ang), sv = sinf(ang);
                    v = (d & 1) ? (other * sv + v * cv) : (v * cv - other * sv);
                }
                const int d  = ncol & (DH - 1);
                const int hh = ncol >> 6;
                const int t  = mrow & (T_ - 1);
                const int bb = mrow >> 11;
                if (mode == 0) {
                    if (isf) ((float*)out)[(size_t)mrow * D_ + ncol] = v;
                    else     ((u16*)out)[(size_t)mrow * D_ + ncol] = f2bf(v);
                } else if (mode == 1) {
                    ((u16*)out)[(((size_t)(bb * H_ + hh) * DH) + d) * T_ + t] = f2bf(v);
                } else {
                    ((u16*)out)[(((size_t)(bb * H_ + hh) * T_) + t) * DH + d] = f2bf(v);
                }
            }
        }
    }
}

// ---------------------------------------------------------------- attention
// MFMA flash attention, fixed-max softmax (scores bounded by soft-cap to 30):
//   p = exp(30*tanh(x/30) - 30) = exp(-60/(z+1)),  z = exp(s/120)
__global__ __launch_bounds__(256) void attn_kernel(const u16* __restrict__ Q,
                                                   const u16* __restrict__ K,
                                                   const u16* __restrict__ Vt,
                                                   const void* __restrict__ lensraw,
                                                   u16* __restrict__ ctx) {
    __shared__ __align__(16) u16 Ps[64 * PSTR];   // Q staging, then P tile
    __shared__ __align__(16) u16 Ks[64 * PSTR];
    __shared__ __align__(16) u16 Vts[64 * PSTR];  // [dim][key]

    const int tid  = threadIdx.x;
    const int wave = tid >> 6;
    const int lane = tid & 63;
    const int quad = lane >> 4;
    const int lr   = lane & 15;
    const int bh   = blockIdx.y;
    const int qs   = blockIdx.x * 64;
    const int b    = bh >> 4;
    const int hh   = bh & 15;
    const int len  = read_len(lensraw, b);
    const size_t base = (size_t)bh * T_ * DH;

    const int srow = tid >> 2;
    const int scb  = (tid & 3) * 16;

    *(uint4*)&Ps[srow * PSTR + scb]     = *(const uint4*)&Q[base + (size_t)(qs + srow) * DH + scb];
    *(uint4*)&Ps[srow * PSTR + scb + 8] = *(const uint4*)&Q[base + (size_t)(qs + srow) * DH + scb + 8];
    __syncthreads();
    const bf16x8 qa0 = *(const bf16x8*)&Ps[(wave * 16 + lr) * PSTR + quad * 8];
    const bf16x8 qa1 = *(const bf16x8*)&Ps[(wave * 16 + lr) * PSTR + 32 + quad * 8];

    f32x4 acc[4];
    float l_loc[4] = {0.f, 0.f, 0.f, 0.f};
    #pragma unroll
    for (int nt = 0; nt < 4; ++nt) acc[nt] = (f32x4){0.f, 0.f, 0.f, 0.f};

    const int smax = min(qs + 63, len - 1);
    const int ktn  = smax / 64 + 1;

    for (int kt = 0; kt < ktn; ++kt) {
        const int ks = kt * 64;
        __syncthreads();
        *(uint4*)&Ks[srow * PSTR + scb]      = *(const uint4*)&K[base + (size_t)(ks + srow) * DH + scb];
        *(uint4*)&Ks[srow * PSTR + scb + 8]  = *(const uint4*)&K[base + (size_t)(ks + srow) * DH + scb + 8];
        *(uint4*)&Vts[srow * PSTR + scb]     = *(const uint4*)&Vt[base + (size_t)srow * T_ + ks + scb];
        *(uint4*)&Vts[srow * PSTR + scb + 8] = *(const uint4*)&Vt[base + (size_t)srow * T_ + ks + scb + 8];
        __syncthreads();

        // QK^T
        f32x4 s[4];
        #pragma unroll
        for (int nt = 0; nt < 4; ++nt) s[nt] = (f32x4){0.f, 0.f, 0.f, 0.f};
        #pragma unroll
        for (int nt = 0; nt < 4; ++nt) {
            bf16x8 kb0 = *(const bf16x8*)&Ks[(nt * 16 + lr) * PSTR + quad * 8];
            bf16x8 kb1 = *(const bf16x8*)&Ks[(nt * 16 + lr) * PSTR + 32 + quad * 8];
            s[nt] = __builtin_amdgcn_mfma_f32_16x16x32_bf16(qa0, kb0, s[nt], 0, 0, 0);
            s[nt] = __builtin_amdgcn_mfma_f32_16x16x32_bf16(qa1, kb1, s[nt], 0, 0, 0);
        }

        // fixed-max softmax (C-layout: qrow = wave*16+quad*4+r, key = ks+nt*16+lr)
        #pragma unroll
        for (int r = 0; r < 4; ++r) {
            const int trow = qs + wave * 16 + quad * 4 + r;
            #pragma unroll
            for (int nt = 0; nt < 4; ++nt) {
                const float z = __expf(s[nt][r] * (1.0f / 120.0f));
                float p = __expf(-60.0f * __builtin_amdgcn_rcpf(z + 1.0f));
                const int col = ks + nt * 16 + lr;
                p = (col > trow || col >= len) ? 0.f : p;
                l_loc[r] += p;
                Ps[(wave * 16 + quad * 4 + r) * PSTR + nt * 16 + lr] = f2bf(p);
            }
        }
        __syncthreads();

        // PV
        bf16x8 pa0 = *(const bf16x8*)&Ps[(wave * 16 + lr) * PSTR + quad * 8];
        bf16x8 pa1 = *(const bf16x8*)&Ps[(wave * 16 + lr) * PSTR + 32 + quad * 8];
        #pragma unroll
        for (int nt = 0; nt < 4; ++nt) {
            bf16x8 vb0 = *(const bf16x8*)&Vts[(nt * 16 + lr) * PSTR + quad * 8];
            bf16x8 vb1 = *(const bf16x8*)&Vts[(nt * 16 + lr) * PSTR + 32 + quad * 8];
            acc[nt] = __builtin_amdgcn_mfma_f32_16x16x32_bf16(pa0, vb0, acc[nt], 0, 0, 0);
            acc[nt] = __builtin_amdgcn_mfma_f32_16x16x32_bf16(pa1, vb1, acc[nt], 0, 0, 0);
        }
    }

    #pragma unroll
    for (int r = 0; r < 4; ++r) {
        float l = l_loc[r];
        #pragma unroll
        for (int off = 1; off < 16; off <<= 1) l += __shfl_xor(l, off);
        const float invl = (l > 0.f) ? (1.0f / l) : 0.f;
        const int qrow = wave * 16 + quad * 4 + r;
        #pragma unroll
        for (int nt = 0; nt < 4; ++nt) {
            ctx[(size_t)(b * T_ + qs + qrow) * D_ + hh * DH + nt * 16 + lr] =
                f2bf(acc[nt][r] * invl);
        }
    }
}

// ---------------------------------------------------------------- launch
extern "C" void kernel_launch(void* const* d_in, const int* in_sizes, int n_in,
                              void* d_out, int out_size, void* d_ws, size_t ws_size,
                              hipStream_t stream) {
    // ws layout: [h:16MB][q:16MB][k:16MB][vt:16MB][wtq|wtk|wtv|wto: 2MB each]
    u16* h = (u16*)d_ws;
    const size_t MD = (size_t)M_ * D_;
    const size_t WD = (size_t)D_ * D_;
    u16* q  = h + MD;
    u16* k  = q + MD;
    u16* vt = k + MD;
    const bool havewt = ws_size >= (4 * MD + 4 * WD) * sizeof(u16);
    u16* wtq = havewt ? (vt + MD)  : nullptr;
    u16* wtk = havewt ? (wtq + WD) : nullptr;
    u16* wtv = havewt ? (wtk + WD) : nullptr;
    u16* wto = havewt ? (wtv + WD) : nullptr;

    ln_kernel<<<M_, 256, 0, stream>>>(d_in[0], d_in[1], d_in[2], h);

    if (havewt) {
        dim3 wgrid(D_ / 64, D_ / 64);
        wconv_kernel<<<wgrid, 256, 0, stream>>>(d_in[3], wtq);
        wconv_kernel<<<wgrid, 256, 0, stream>>>(d_in[5], wtk);
        wconv_kernel<<<wgrid, 256, 0, stream>>>(d_in[7], wtv);
        wconv_kernel<<<wgrid, 256, 0, stream>>>(d_in[9], wto);

        dim3 g128(D_ / 128, M_ / 128);
        gemm128_kernel<<<g128, 256, 0, stream>>>(h, wtq, d_in[3], d_in[4], q, 2);
        gemm128_kernel<<<g128, 256, 0, stream>>>(h, wtk, d_in[5], d_in[6], k, 2);
        gemm128_kernel<<<g128, 256, 0, stream>>>(h, wtv, d_in[7], d_in[8], vt, 1);
        attn_kernel<<<dim3(T_ / 64, NB * H_), 256, 0, stream>>>(q, k, vt, d_in[13], h);
        gemm128_kernel<<<g128, 256, 0, stream>>>(h, wto, d_in[9], d_in[10], d_out, 0);
    } else {
        dim3 ggrid(D_ / 64, M_ / 128);
        gemm_kernel<<<ggrid, 256, 0, stream>>>(h, d_in[3], d_in[4], q, 2);
        gemm_kernel<<<ggrid, 256, 0, stream>>>(h, d_in[5], d_in[6], k, 2);
        gemm_kernel<<<ggrid, 256, 0, stream>>>(h, d_in[7], d_in[8], vt, 1);
        attn_kernel<<<dim3(T_ / 64, NB * H_), 256, 0, stream>>>(q, k, vt, d_in[13], h);
        gemm_kernel<<<ggrid, 256, 0, stream>>>(h, d_in[9], d_in[10], d_out, 0);
    }
}